// Round 8
// baseline (120.913 us; speedup 1.0000x reference)
//
#include <hip/hip_runtime.h>

// CARAFE forward: N=8, C=128, H=64, W=64, k=5, G=1, s=2.
// out[n,c,2h+p,2w+q] = sum_{i,j} feat[n,c,h+i-2,w+j-2] * masks[n,i*5+j,2h+p,2w+q]
//
// Round 8: stop fighting the register allocator. Rounds 3-7 pinned masks in
// VGPRs -> compiler spilled to AGPR (V+A=128/wave) -> 16-wave/CU cap ->
// latency-bound 38-46us. New structure needs ~48 regs TOTAL: masks are
// STREAMED from global (L1/L2-resident, VMEM pipe) per tap; features come
// from channel-interleaved LDS (1 ds_read_b128 serves 4 ch x 4 pq outputs).
// Target ~28 waves/CU; DS ~10us, VALU ~7us, HBM ~18us -> memory-bound.

#define KK 5
#define PAD 2
#define CIN 128
#define HH 64
#define WW 64
#define HO 128
#define WO 128
#define NG 4                     // channel groups (= waves) per block
#define GC 4                     // channels per group, interleaved in LDS
#define CH_PER_BLOCK (NG * GC)   // 16
#define LCOLS 68                 // 2 halo | 64 data | 2 halo

__global__ __launch_bounds__(256)
void carafe_fwd(const float* __restrict__ feat,
                const float* __restrict__ masks,
                float* __restrict__ out) {
    __shared__ float lds[NG][KK][LCOLS][GC];   // 21760 B -> 7 blocks/CU

    const int tid  = threadIdx.x;
    const int lane = tid & 63;          // low-res w
    const int g    = tid >> 6;          // wave id = channel group
    // XCD swizzle: consecutive blockIdx.x round-robin across 8 XCDs; remap so
    // each XCD owns a contiguous h-strip of 8 (feature-row halo reuse in L2).
    const int bx   = blockIdx.x;
    const int h    = ((bx & 7) << 3) | (bx >> 3);   // bijective on 0..63
    const int c0   = blockIdx.y * CH_PER_BLOCK;
    const int n    = blockIdx.z;

    // ---- stage features, 4-channel interleaved; halo & OOB rows zeroed ----
    const float* fb = feat + ((size_t)n * CIN + c0) * HH * WW;
    #pragma unroll
    for (int t = 0; t < 6; ++t) {
        int idx = t * 256 + tid;                 // 0..1535, 1360 live
        if (idx < NG * KK * LCOLS) {
            int gg  = idx / (KK * LCOLS);
            int rem = idx - gg * (KK * LCOLS);
            int r   = rem / LCOLS;
            int c   = rem - r * LCOLS;
            int rr  = h - PAD + r;
            int fc  = c - 2;
            float4 v = make_float4(0.f, 0.f, 0.f, 0.f);
            if ((unsigned)rr < (unsigned)HH && (unsigned)fc < (unsigned)WW) {
                const float* s = fb + ((size_t)(gg * GC) * HH + rr) * WW + fc;
                v.x = s[0 * HH * WW];
                v.y = s[1 * HH * WW];
                v.z = s[2 * HH * WW];
                v.w = s[3 * HH * WW];
            }
            *(float4*)&lds[gg][r][c][0] = v;
        }
    }
    __syncthreads();

    // ---- compute: per tap {1 ds_read_b128 + 2 global float2 + 16 fmac} ----
    // masks stay in cache (25.6 KB per (n,h) row-pair set); no register residency.
    const float* mb = masks + (size_t)n * (KK * KK) * HO * WO
                            + (size_t)(2 * h) * WO + 2 * lane;

    float2 acc[GC][2];                  // [channel][p], float2 over q
    #pragma unroll
    for (int ci = 0; ci < GC; ++ci) {
        acc[ci][0] = make_float2(0.f, 0.f);
        acc[ci][1] = make_float2(0.f, 0.f);
    }

    #pragma unroll
    for (int i = 0; i < KK; ++i) {
        #pragma unroll
        for (int j = 0; j < KK; ++j) {
            const int k = i * KK + j;
            // feature col (lane + j - 2) lives at LDS col (lane + j)
            const float4 f4 = *(const float4*)&lds[g][i][lane + j][0];
            const float2 m0 = *(const float2*)(mb + (size_t)k * HO * WO);       // row 2h
            const float2 m1 = *(const float2*)(mb + (size_t)k * HO * WO + WO);  // row 2h+1
            acc[0][0].x += f4.x * m0.x;  acc[0][0].y += f4.x * m0.y;
            acc[0][1].x += f4.x * m1.x;  acc[0][1].y += f4.x * m1.y;
            acc[1][0].x += f4.y * m0.x;  acc[1][0].y += f4.y * m0.y;
            acc[1][1].x += f4.y * m1.x;  acc[1][1].y += f4.y * m1.y;
            acc[2][0].x += f4.z * m0.x;  acc[2][0].y += f4.z * m0.y;
            acc[2][1].x += f4.z * m1.x;  acc[2][1].y += f4.z * m1.y;
            acc[3][0].x += f4.w * m0.x;  acc[3][0].y += f4.w * m0.y;
            acc[3][1].x += f4.w * m1.x;  acc[3][1].y += f4.w * m1.y;
        }
    }

    // ---- store: 4 ch x 2 rows, float2 (both q), coalesced ----
    float* ob = out + ((size_t)n * CIN + c0 + g * GC) * HO * WO
                    + (size_t)(2 * h) * WO + 2 * lane;
    #pragma unroll
    for (int ci = 0; ci < GC; ++ci) {
        *(float2*)(ob + (size_t)ci * HO * WO)      = acc[ci][0];
        *(float2*)(ob + (size_t)ci * HO * WO + WO) = acc[ci][1];
    }
}

extern "C" void kernel_launch(void* const* d_in, const int* in_sizes, int n_in,
                              void* d_out, int out_size, void* d_ws, size_t ws_size,
                              hipStream_t stream) {
    const float* feat  = (const float*)d_in[0];
    const float* masks = (const float*)d_in[1];
    float* out = (float*)d_out;

    dim3 grid(HH, CIN / CH_PER_BLOCK, 8);   // (h-swizzled, c-group, n) = (64, 8, 8)
    dim3 block(256);
    carafe_fwd<<<grid, block, 0, stream>>>(feat, masks, out);
}